// Round 18
// baseline (734.367 us; speedup 1.0000x reference)
//
#include <hip/hip_runtime.h>
#include <hip/hip_bf16.h>
#include <stdint.h>
#include <stdio.h>

// Problem geometry (fixed by the reference)
#define M_DIM 8192    // 4*2048
#define K_DIM 4096    // IN_FEATURES
#define N_DIM 11008   // OUT_FEATURES

#define BM 256
#define BN 256
#define BK 64
#define NT (K_DIM / BK)           // 64 K-tiles (power of 2 -> & wrap ok)
#define TILES_M (M_DIM / BM)      // 32
#define TILES_N (N_DIM / BN)      // 43
#define NWG (TILES_M * TILES_N)   // 1376

typedef __bf16 bf16x8 __attribute__((ext_vector_type(8)));
typedef float f32x4 __attribute__((ext_vector_type(4)));

__device__ __constant__ float kFp4Code[16] = {
    0.0f,           0.0052083333f,  0.6666666666f, 1.0f,
    0.3333333333f,  0.5f,           0.1666666666f, 0.25f,
    -0.0f,          -0.0052083333f, -0.6666666666f, -1.0f,
    -0.3333333333f, -0.5f,          -0.1666666666f, -0.25f
};

// ---------------------------------------------------------------------------
// Kernel 1 (fused prep): blocks [0, 22016): FP4 dequant -> bf16 W;
//                        blocks [22016, 38400): x fp32 -> bf16.
// ---------------------------------------------------------------------------
#define DEQ_BLOCKS 22016   // 45,088,768 / 8 / 256
#define CVT_BLOCKS 16384   // 33,554,432 / 8 / 256

__global__ __launch_bounds__(256) void prep_kernel(
    const int* __restrict__ codes, const float* __restrict__ absmax,
    const float* __restrict__ x,
    __hip_bfloat16* __restrict__ w, __hip_bfloat16* __restrict__ y)
{
    if (blockIdx.x < DEQ_BLOCKS) {
        __shared__ float lut[16];
        if (threadIdx.x < 16) lut[threadIdx.x] = kFp4Code[threadIdx.x];
        __syncthreads();

        const int t = blockIdx.x * 256 + threadIdx.x;  // < 5,636,096
        const int4* cp = (const int4*)codes;
        const int4 c0 = cp[2 * t];
        const int4 c1 = cp[2 * t + 1];
        const float am = absmax[t >> 3];

        union { int4 v; __hip_bfloat16 h[8]; } u;
        u.h[0] = __float2bfloat16(lut[c0.x & 15] * am);
        u.h[1] = __float2bfloat16(lut[c0.y & 15] * am);
        u.h[2] = __float2bfloat16(lut[c0.z & 15] * am);
        u.h[3] = __float2bfloat16(lut[c0.w & 15] * am);
        u.h[4] = __float2bfloat16(lut[c1.x & 15] * am);
        u.h[5] = __float2bfloat16(lut[c1.y & 15] * am);
        u.h[6] = __float2bfloat16(lut[c1.z & 15] * am);
        u.h[7] = __float2bfloat16(lut[c1.w & 15] * am);
        ((int4*)w)[t] = u.v;
    } else {
        const int t = (blockIdx.x - DEQ_BLOCKS) * 256 + threadIdx.x;  // < 4,194,304
        const float4* xp = (const float4*)x;
        const float4 a = xp[2 * t];
        const float4 b = xp[2 * t + 1];
        union { int4 v; __hip_bfloat16 h[8]; } u;
        u.h[0] = __float2bfloat16(a.x);
        u.h[1] = __float2bfloat16(a.y);
        u.h[2] = __float2bfloat16(a.z);
        u.h[3] = __float2bfloat16(a.w);
        u.h[4] = __float2bfloat16(b.x);
        u.h[5] = __float2bfloat16(b.y);
        u.h[6] = __float2bfloat16(b.z);
        u.h[7] = __float2bfloat16(b.w);
        ((int4*)y)[t] = u.v;
    }
}

// ---------------------------------------------------------------------------
// Kernel 2: bf16 GEMM, C = A * B^T + bias  (256x256 tile, TWO windows/K-tile)
//
// Round-18 change vs round-11/17: vmcnt(8) -> vmcnt(4) at both windows,
// which confirms each staged pair ONE window earlier. Consequence: bvHi(t)
// ({Ahi,Bhi}(t), staged W0(t-1)) is now all-waves-confirmed at W1(t-1)'s
// vmcnt(4)+bar#1 -> its 4 ds_reads move from MID-MFMA-CLUSTER to pre-bar.
// Both 16-MFMA clusters become interruption-free (the mid-cluster lgkm
// drain was a ~120-200 cyc serial bubble per window).
//
// vmcnt ledger (pair-stream FIFO, 4 gloads/pair):
//  at W0(t) wait: outstanding = {Alo,Blo}(t+1)[W1(t-1)] + {Ahi,Bhi}(t+1)
//  [W0(t)] = 8 -> vmcnt(4) confirms {Alo,Blo}(t+1) (needed W0(t+1) pre-bar).
//  at W1(t) wait: outstanding = {Ahi,Bhi}(t+1) + {Alo,Blo}(t+2)[W1(t)] = 8
//  -> vmcnt(4) confirms {Ahi,Bhi}(t+1) (needed W0(t+1) pre-bar: bvHi(t+1);
//  W1(t+1) pre-bar: avHi(t+1)). Each confirmed pair was issued one full
//  window (~1250 cyc) earlier >= L2/HBM latency (brick-shared, mostly L2).
// Cross-wave safety: every read's producing pair is vmcnt-confirmed by ALL
//  waves >= 1 barrier before the read (audited above). Overwrite ledger:
//  identical to round 11 except bvHi's last read moves EARLIER (safer).
// Window structure:
//  W0: stage {Ahi,Bhi}(t+1)->LB1; read avLo,bvLo,bvHi(t) [16 b128];
//      vmcnt(4); bar; SB(0); prio1; Q00 x16; Q01 x16; prio0; bar.
//  W1: stage {Alo,Blo}(t+2)->LB; read avHi(t) [8];
//      vmcnt(4); bar; SB(0); prio1; Q11 x16; Q10 x16; prio0; bar.
// 2D brick order (round-9: FETCH 1.52->0.62 GB). XOR involution swizzle
// (round-2: 0 conflicts). LDS 128KB: 2 dbuf x {Alo@0,Ahi@16K,Blo@32K,Bhi@48K}.
// ---------------------------------------------------------------------------
#define STAGE(gbase, eoff, loff)                                              \
    __builtin_amdgcn_global_load_lds(                                         \
        (const __attribute__((address_space(1))) void*)((gbase) + (eoff)),    \
        (__attribute__((address_space(3))) void*)(lds + (loff)), 16, 0, 0)

// 16 MFMAs: one quadrant (4m x 2n x 2ks), ks-outer for dependence distance 8
__device__ __forceinline__ void mfma_half(
    f32x4 (&accq)[4][2], bf16x8 (&av)[4][2], bf16x8 (&bv)[2][2])
{
#pragma unroll
    for (int ks = 0; ks < 2; ++ks)
#pragma unroll
        for (int m = 0; m < 4; ++m)
#pragma unroll
            for (int n = 0; n < 2; ++n)
                accq[m][n] = __builtin_amdgcn_mfma_f32_16x16x32_bf16(
                    av[m][ks], bv[n][ks], accq[m][n], 0, 0, 0);
}

template<int BUF>
__device__ __forceinline__ void tile_body(
    int t, f32x4 (&acc)[4][4][2],
    const __hip_bfloat16* __restrict__ A, const __hip_bfloat16* __restrict__ B,
    char* lds,
    const int (&sA_lo)[2], const int (&sA_hi)[2],
    const int (&sB_lo)[2], const int (&sB_hi)[2],
    int dst0, int dst1,
    const char* pA0, const char* pA1, const char* pB0, const char* pB1)
{
    constexpr int LB  = BUF * 65536;         // this tile's buffer
    constexpr int LB1 = (BUF ^ 1) * 65536;   // (t+1)'s buffer
    const int koff1 = ((t + 1) & (NT - 1)) * 64;   // wave-uniform (SALU)
    const int koff2 = ((t + 2) & (NT - 1)) * 64;

    bf16x8 avLo[4][2], avHi[4][2], bvLo[2][2], bvHi[2][2];

    // ================= W0 =================
    STAGE(A, sA_hi[0] + koff1, LB1 + 16384 + dst0);
    STAGE(A, sA_hi[1] + koff1, LB1 + 16384 + dst1);
    STAGE(B, sB_hi[0] + koff1, LB1 + 49152 + dst0);
    STAGE(B, sB_hi[1] + koff1, LB1 + 49152 + dst1);
    // pre-bar reads: avLo,bvLo(t) (confirmed W1(t-1)); bvHi(t) (confirmed
    // W1(t-1) via vmcnt(4) -- the round-18 change)
#pragma unroll
    for (int m = 0; m < 4; ++m) {
        avLo[m][0] = *(const bf16x8*)(pA0 + LB + m * 2048);
        avLo[m][1] = *(const bf16x8*)(pA1 + LB + m * 2048);
    }
#pragma unroll
    for (int n = 0; n < 2; ++n) {
        bvLo[n][0] = *(const bf16x8*)(pB0 + LB + n * 2048);
        bvLo[n][1] = *(const bf16x8*)(pB1 + LB + n * 2048);
    }
#pragma unroll
    for (int n = 0; n < 2; ++n) {
        bvHi[n][0] = *(const bf16x8*)(pB0 + LB + 16384 + n * 2048);
        bvHi[n][1] = *(const bf16x8*)(pB1 + LB + 16384 + n * 2048);
    }
    asm volatile("s_waitcnt vmcnt(4)" ::: "memory");
    __builtin_amdgcn_s_barrier();
    __builtin_amdgcn_sched_barrier(0);     // nothing crosses bar#1
    __builtin_amdgcn_s_setprio(1);
    mfma_half(acc[0], avLo, bvLo);         // Q(0,0)
    mfma_half(acc[1], avLo, bvHi);         // Q(0,1)  (no mid-cluster read)
    __builtin_amdgcn_s_setprio(0);
    __builtin_amdgcn_s_barrier();

    // ================= W1 =================
    STAGE(A, sA_lo[0] + koff2, LB + dst0);
    STAGE(A, sA_lo[1] + koff2, LB + dst1);
    STAGE(B, sB_lo[0] + koff2, LB + 32768 + dst0);
    STAGE(B, sB_lo[1] + koff2, LB + 32768 + dst1);
    // pre-bar read avHi(t) (cross-wave-confirmed at W0(t) bar#1)
#pragma unroll
    for (int m = 0; m < 4; ++m) {
        avHi[m][0] = *(const bf16x8*)(pA0 + LB + 16384 + m * 2048);
        avHi[m][1] = *(const bf16x8*)(pA1 + LB + 16384 + m * 2048);
    }
    asm volatile("s_waitcnt vmcnt(4)" ::: "memory");
    __builtin_amdgcn_s_barrier();
    __builtin_amdgcn_sched_barrier(0);
    __builtin_amdgcn_s_setprio(1);
    mfma_half(acc[2], avHi, bvHi);         // Q(1,1)
    mfma_half(acc[3], avHi, bvLo);         // Q(1,0)
    __builtin_amdgcn_s_setprio(0);
    __builtin_amdgcn_s_barrier();
}

__global__ __launch_bounds__(512, 2) void gemm_bf16_8phase(
    const __hip_bfloat16* __restrict__ A, const __hip_bfloat16* __restrict__ B,
    const float* __restrict__ bias, float* __restrict__ C)
{
    extern __shared__ char lds[];  // 131072 B

    const int tid = threadIdx.x;
    const int lane = tid & 63;
    const int wid = tid >> 6;       // 0..7
    const int wr = wid >> 2;        // 0..1 (M split)
    const int wc = wid & 3;         // 0..3 (N split)
    const int l15 = lane & 15;
    const int kgrp = lane >> 4;

    // XCD stripe (bijective) + 2D brick order (round-9): per-XCD 8x4 bricks.
    const int wg = blockIdx.x;
    const int s = (wg & 7) * (NWG / 8) + (wg >> 3);
    int bm, bn;
    if (s < 1280) {                 // 10 groups of width 4 (8x4 bricks)
        const int g = s >> 7;
        const int j = s & 127;
        bm = j >> 2;
        bn = g * 4 + (j & 3);
    } else {                        // last group: width 3
        const int j = s - 1280;     // 0..95
        bm = j / 3;
        bn = 40 + j % 3;
    }
    const int m0 = bm * BM;
    const int n0 = bn * BN;

    // ---- Precomputed stage-source element offsets (per lane, once) ----
    int sA_lo[2], sA_hi[2], sB_lo[2], sB_hi[2];
#pragma unroll
    for (int c = 0; c < 2; ++c) {
        const int idx = c * 512 + tid;          // 0..1023 chunk id (linear LDS)
        const int row = idx >> 3;               // 0..127
        const int scol = (idx & 7) ^ (row & 7); // pre-swizzled source chunk
        sA_lo[c] = (m0 + row) * K_DIM + scol * 8;
        sA_hi[c] = sA_lo[c] + 128 * K_DIM;
        sB_lo[c] = (n0 + row) * K_DIM + scol * 8;
        sB_hi[c] = sB_lo[c] + 128 * K_DIM;
    }
    const int dst0 = wid * 1024;          // (c*512 + wid*64)*16, c=0
    const int dst1 = 8192 + wid * 1024;   // c=1

    // ---- Precomputed fragment-read base pointers (buf0; buf1 = +65536) ----
    const int xlo = l15 & 7;
    const char* pA0 = lds + (wr * 64 + l15) * 128 + ((kgrp) ^ xlo) * 16;
    const char* pA1 = lds + (wr * 64 + l15) * 128 + ((4 + kgrp) ^ xlo) * 16;
    const char* pB0 = lds + 32768 + (wc * 32 + l15) * 128 + ((kgrp) ^ xlo) * 16;
    const char* pB1 = lds + 32768 + (wc * 32 + l15) * 128 + ((4 + kgrp) ^ xlo) * 16;

    // acc quadrants: 0=(0,0) 1=(0,1) 2=(1,1) 3=(1,0)  (mq,nq)
    f32x4 acc[4][4][2];
#pragma unroll
    for (int q = 0; q < 4; ++q)
#pragma unroll
        for (int m = 0; m < 4; ++m)
#pragma unroll
            for (int n = 0; n < 2; ++n)
                acc[q][m][n] = (f32x4){0.f, 0.f, 0.f, 0.f};

    // Prologue pair-stream (FIFO matches steady state):
    //  {Alo(0),Blo(0)} ; {Ahi(0),Bhi(0)} ; {Alo(1),Blo(1)}
    STAGE(A, sA_lo[0], dst0);                 STAGE(A, sA_lo[1], dst1);
    STAGE(B, sB_lo[0], 32768 + dst0);         STAGE(B, sB_lo[1], 32768 + dst1);
    STAGE(A, sA_hi[0], 16384 + dst0);         STAGE(A, sA_hi[1], 16384 + dst1);
    STAGE(B, sB_hi[0], 49152 + dst0);         STAGE(B, sB_hi[1], 49152 + dst1);
    STAGE(A, sA_lo[0] + 64, 65536 + dst0);    STAGE(A, sA_lo[1] + 64, 65536 + dst1);
    STAGE(B, sB_lo[0] + 64, 98304 + dst0);    STAGE(B, sB_lo[1] + 64, 98304 + dst1);
    // vmcnt(4): confirms {Alo,Blo}(0) AND {Ahi,Bhi}(0); leaves {Alo,Blo}(1)
    asm volatile("s_waitcnt vmcnt(4)" ::: "memory");
    __builtin_amdgcn_s_barrier();

    for (int t = 0; t < NT; t += 2) {
        tile_body<0>(t,     acc, A, B, lds, sA_lo, sA_hi, sB_lo, sB_hi,
                     dst0, dst1, pA0, pA1, pB0, pB1);
        tile_body<1>(t + 1, acc, A, B, lds, sA_lo, sA_hi, sB_lo, sB_hi,
                     dst0, dst1, pA0, pA1, pB0, pB1);
    }

    // Epilogue (C/D layout: col = lane&15, row = (lane>>4)*4 + reg).
    // Nontemporal: C written once, never re-read -> don't churn L3.
#pragma unroll
    for (int q = 0; q < 4; ++q) {
        const int mqe = q >> 1;
        const int nqe = (q == 1 || q == 2) ? 1 : 0;
#pragma unroll
        for (int n = 0; n < 2; ++n) {
            const int col = n0 + nqe * 128 + wc * 32 + n * 16 + l15;
            const float bval = bias[col];
#pragma unroll
            for (int m = 0; m < 4; ++m) {
                const int row = m0 + mqe * 128 + wr * 64 + m * 16 + kgrp * 4;
#pragma unroll
                for (int r = 0; r < 4; ++r)
                    __builtin_nontemporal_store(acc[q][m][n][r] + bval,
                        &C[(size_t)(row + r) * N_DIM + col]);
            }
        }
    }
}

// ---------------------------------------------------------------------------
extern "C" void kernel_launch(void* const* d_in, const int* in_sizes, int n_in,
                              void* d_out, int out_size, void* d_ws, size_t ws_size,
                              hipStream_t stream)
{
    const float* x      = (const float*)d_in[0];  // [4,2048,4096] f32
    const int*   codes  = (const int*)d_in[1];    // [704512,64] i32
    const float* absmax = (const float*)d_in[2];  // [704512] f32
    const float* bias   = (const float*)d_in[3];  // [11008] f32
    float* out = (float*)d_out;                   // [4,2048,11008] f32

    const size_t w_bytes = (size_t)N_DIM * K_DIM * sizeof(__hip_bfloat16);
    const size_t x_bytes = (size_t)M_DIM * K_DIM * sizeof(__hip_bfloat16);
    if (ws_size < w_bytes + x_bytes) {
        fprintf(stderr, "kernel_launch: ws_size=%zu < needed %zu\n",
                ws_size, w_bytes + x_bytes);
        return;
    }
    __hip_bfloat16* wbf = (__hip_bfloat16*)d_ws;
    __hip_bfloat16* xbf = (__hip_bfloat16*)((char*)d_ws + w_bytes);

    // Allow 128 KiB dynamic LDS (idempotent host-side call; capture-safe).
    hipFuncSetAttribute((const void*)gemm_bf16_8phase,
                        hipFuncAttributeMaxDynamicSharedMemorySize, 131072);

    prep_kernel<<<dim3(DEQ_BLOCKS + CVT_BLOCKS), dim3(256), 0, stream>>>(
        codes, absmax, x, wbf, xbf);
    gemm_bf16_8phase<<<dim3(NWG), dim3(512), 131072, stream>>>(xbf, wbf, bias, out);
}

// Round 19
// 730.681 us; speedup vs baseline: 1.0050x; 1.0050x over previous
//
#include <hip/hip_runtime.h>
#include <hip/hip_bf16.h>
#include <stdint.h>
#include <stdio.h>

// Problem geometry (fixed by the reference)
#define M_DIM 8192    // 4*2048
#define K_DIM 4096    // IN_FEATURES
#define N_DIM 11008   // OUT_FEATURES

#define BM 256
#define BN 256
#define BK 64
#define NT (K_DIM / BK)           // 64 K-tiles (power of 2 -> & wrap ok)
#define TILES_M (M_DIM / BM)      // 32
#define TILES_N (N_DIM / BN)      // 43
#define NWG (TILES_M * TILES_N)   // 1376

typedef __bf16 bf16x8 __attribute__((ext_vector_type(8)));
typedef float f32x4 __attribute__((ext_vector_type(4)));

__device__ __constant__ float kFp4Code[16] = {
    0.0f,           0.0052083333f,  0.6666666666f, 1.0f,
    0.3333333333f,  0.5f,           0.1666666666f, 0.25f,
    -0.0f,          -0.0052083333f, -0.6666666666f, -1.0f,
    -0.3333333333f, -0.5f,          -0.1666666666f, -0.25f
};

// ---------------------------------------------------------------------------
// Kernel 1 (fused prep): blocks [0, 22016): FP4 dequant -> bf16 W;
//                        blocks [22016, 38400): x fp32 -> bf16.
// ---------------------------------------------------------------------------
#define DEQ_BLOCKS 22016   // 45,088,768 / 8 / 256
#define CVT_BLOCKS 16384   // 33,554,432 / 8 / 256

__global__ __launch_bounds__(256) void prep_kernel(
    const int* __restrict__ codes, const float* __restrict__ absmax,
    const float* __restrict__ x,
    __hip_bfloat16* __restrict__ w, __hip_bfloat16* __restrict__ y)
{
    if (blockIdx.x < DEQ_BLOCKS) {
        __shared__ float lut[16];
        if (threadIdx.x < 16) lut[threadIdx.x] = kFp4Code[threadIdx.x];
        __syncthreads();

        const int t = blockIdx.x * 256 + threadIdx.x;  // < 5,636,096
        const int4* cp = (const int4*)codes;
        const int4 c0 = cp[2 * t];
        const int4 c1 = cp[2 * t + 1];
        const float am = absmax[t >> 3];

        union { int4 v; __hip_bfloat16 h[8]; } u;
        u.h[0] = __float2bfloat16(lut[c0.x & 15] * am);
        u.h[1] = __float2bfloat16(lut[c0.y & 15] * am);
        u.h[2] = __float2bfloat16(lut[c0.z & 15] * am);
        u.h[3] = __float2bfloat16(lut[c0.w & 15] * am);
        u.h[4] = __float2bfloat16(lut[c1.x & 15] * am);
        u.h[5] = __float2bfloat16(lut[c1.y & 15] * am);
        u.h[6] = __float2bfloat16(lut[c1.z & 15] * am);
        u.h[7] = __float2bfloat16(lut[c1.w & 15] * am);
        ((int4*)w)[t] = u.v;
    } else {
        const int t = (blockIdx.x - DEQ_BLOCKS) * 256 + threadIdx.x;  // < 4,194,304
        const float4* xp = (const float4*)x;
        const float4 a = xp[2 * t];
        const float4 b = xp[2 * t + 1];
        union { int4 v; __hip_bfloat16 h[8]; } u;
        u.h[0] = __float2bfloat16(a.x);
        u.h[1] = __float2bfloat16(a.y);
        u.h[2] = __float2bfloat16(a.z);
        u.h[3] = __float2bfloat16(a.w);
        u.h[4] = __float2bfloat16(b.x);
        u.h[5] = __float2bfloat16(b.y);
        u.h[6] = __float2bfloat16(b.z);
        u.h[7] = __float2bfloat16(b.w);
        ((int4*)y)[t] = u.v;
    }
}

// ---------------------------------------------------------------------------
// Kernel 2: bf16 GEMM, C = A * B^T + bias  (256x256, 2 windows/K-tile,
//                                           TRAILING-READ pipeline)
//
// Round-19 theory: rounds 5-18's serialization was caused by the "memory"
// clobber on the vmcnt asm -- it forces hipcc to drain lgkmcnt(0) at the asm
// (asm may alias LDS), so the ds_read queue was ALWAYS empty during the MFMA
// cluster. Fix: (1) ds_reads move AFTER the MFMA cluster, consumed one
// window later (compiler inserts fine-grained lgkm waits before next
// window's MFMAs); (2) vmcnt asm has NO memory clobber; program-order
// pinning via sched_barrier(0) on every boundary. The LDS queue now drains
// UNDER the next MFMA cluster.
//
// Window structure (tile t, LB=(t&1)*64KB, LB1=other):
//  W0(t): [stage {Ahi,Bhi}(t+1)->LB1][SB0 vmcnt(4) SB0][bar][SB0]
//         [prio1 Q00(avLo,bvLo) Q01(avLo,bvHi) prio0]     <- regs from W1(t-1)
//         [SB0][trail-read avHi(t)<-LB (8)][SB0][bar]
//  W1(t): [stage {Alo,Blo}(t+2)->LB][SB0 vmcnt(4) SB0][bar][SB0]
//         [prio1 Q11(avHi,bvHi) Q10(avHi,bvLo) prio0]
//         [SB0][trail-read avLo,bvLo,bvHi(t+1)<-LB1 (16, consumption
//          order: bvLo/avLo interleaved ks0-first, bvHi last)][SB0][bar]
//
// vmcnt ledger (pair FIFO, 4 gloads/pair, 8 outstanding at each wait):
//  W0(t) vmcnt(4) confirms {Alo,Blo}(t+1) -> needed by W1(t) trail-reads
//   (after bar#1(W1(t)), which follows W0(t)'s vmcnt+bar in all waves).
//  W1(t) vmcnt(4) confirms {Ahi,Bhi}(t+1) -> needed by W1(t) trail-read
//   bvHi(t+1) (after this window's own vmcnt+bar#1) and W0(t+1)'s avHi... 
//   avHi(t+1) read in W0(t+1) trail (after bar#1(W0(t+1))). All confirmed
//   >=1 barrier before issue, all waves.
// Overwrite ledger: each trail-read completes no later than its consuming
//  cluster's lgkm wait (next window), >=1 barrier before its region is
//  re-staged (regions re-staged >=2 windows after last read issue). Trail
//  reads never target the buffer being staged in the same window.
// Register WAR (trail reads overwrite arrays consumed by this window's
//  cluster): SSA -- compiler renames; in-order issue puts MFMAs first.
// 2D brick order (round-9). XOR involution swizzle (round-2, 0 conflicts).
// LDS 128KB: 2 dbuf x {Alo@0,Ahi@16K,Blo@32K,Bhi@48K}.
// ---------------------------------------------------------------------------
#define STAGE(gbase, eoff, loff)                                              \
    __builtin_amdgcn_global_load_lds(                                         \
        (const __attribute__((address_space(1))) void*)((gbase) + (eoff)),    \
        (__attribute__((address_space(3))) void*)(lds + (loff)), 16, 0, 0)

#define SB0() __builtin_amdgcn_sched_barrier(0)

// 16 MFMAs: one quadrant (4m x 2n x 2ks), ks-outer for dependence distance 8
__device__ __forceinline__ void mfma_half(
    f32x4 (&accq)[4][2], bf16x8 (&av)[4][2], bf16x8 (&bv)[2][2])
{
#pragma unroll
    for (int ks = 0; ks < 2; ++ks)
#pragma unroll
        for (int m = 0; m < 4; ++m)
#pragma unroll
            for (int n = 0; n < 2; ++n)
                accq[m][n] = __builtin_amdgcn_mfma_f32_16x16x32_bf16(
                    av[m][ks], bv[n][ks], accq[m][n], 0, 0, 0);
}

template<int BUF>
__device__ __forceinline__ void tile_body(
    int t, f32x4 (&acc)[4][4][2],
    const __hip_bfloat16* __restrict__ A, const __hip_bfloat16* __restrict__ B,
    char* lds,
    const int (&sA_lo)[2], const int (&sA_hi)[2],
    const int (&sB_lo)[2], const int (&sB_hi)[2],
    int dst0, int dst1,
    const char* pA0, const char* pA1, const char* pB0, const char* pB1,
    bf16x8 (&avLo)[4][2], bf16x8 (&avHi)[4][2],
    bf16x8 (&bvLo)[2][2], bf16x8 (&bvHi)[2][2])
{
    constexpr int LB  = BUF * 65536;         // this tile's buffer
    constexpr int LB1 = (BUF ^ 1) * 65536;   // (t+1)'s buffer
    const int koff1 = ((t + 1) & (NT - 1)) * 64;   // wave-uniform (SALU)
    const int koff2 = ((t + 2) & (NT - 1)) * 64;

    // ================= W0 =================
    STAGE(A, sA_hi[0] + koff1, LB1 + 16384 + dst0);
    STAGE(A, sA_hi[1] + koff1, LB1 + 16384 + dst1);
    STAGE(B, sB_hi[0] + koff1, LB1 + 49152 + dst0);
    STAGE(B, sB_hi[1] + koff1, LB1 + 49152 + dst1);
    SB0();
    asm volatile("s_waitcnt vmcnt(4)");   // NO memory clobber (round-19)
    SB0();
    __builtin_amdgcn_s_barrier();
    SB0();
    __builtin_amdgcn_s_setprio(1);
    mfma_half(acc[0], avLo, bvLo);         // Q(0,0) -- operands read W1(t-1)
    mfma_half(acc[1], avLo, bvHi);         // Q(0,1)
    __builtin_amdgcn_s_setprio(0);
    SB0();
    // trail-read avHi(t) <- LB (consumed W1(t)); drains under W1's cluster
#pragma unroll
    for (int m = 0; m < 4; ++m) {
        avHi[m][0] = *(const bf16x8*)(pA0 + LB + 16384 + m * 2048);
        avHi[m][1] = *(const bf16x8*)(pA1 + LB + 16384 + m * 2048);
    }
    SB0();
    __builtin_amdgcn_s_barrier();

    // ================= W1 =================
    STAGE(A, sA_lo[0] + koff2, LB + dst0);
    STAGE(A, sA_lo[1] + koff2, LB + dst1);
    STAGE(B, sB_lo[0] + koff2, LB + 32768 + dst0);
    STAGE(B, sB_lo[1] + koff2, LB + 32768 + dst1);
    SB0();
    asm volatile("s_waitcnt vmcnt(4)");
    SB0();
    __builtin_amdgcn_s_barrier();
    SB0();
    __builtin_amdgcn_s_setprio(1);
    mfma_half(acc[2], avHi, bvHi);         // Q(1,1)
    mfma_half(acc[3], avHi, bvLo);         // Q(1,0)
    __builtin_amdgcn_s_setprio(0);
    SB0();
    // trail-read avLo,bvLo,bvHi(t+1) <- LB1, consumption order for W0(t+1):
    // first MFMA needs avLo[0][0]+bvLo[0][0] -> interleave, ks0 group first.
#pragma unroll
    for (int m = 0; m < 4; ++m) {
        if (m < 2) bvLo[m][0] = *(const bf16x8*)(pB0 + LB1 + m * 2048);
        avLo[m][0] = *(const bf16x8*)(pA0 + LB1 + m * 2048);
    }
#pragma unroll
    for (int m = 0; m < 4; ++m) {
        if (m < 2) bvLo[m][1] = *(const bf16x8*)(pB1 + LB1 + m * 2048);
        avLo[m][1] = *(const bf16x8*)(pA1 + LB1 + m * 2048);
    }
#pragma unroll
    for (int n = 0; n < 2; ++n) {
        bvHi[n][0] = *(const bf16x8*)(pB0 + LB1 + 16384 + n * 2048);
        bvHi[n][1] = *(const bf16x8*)(pB1 + LB1 + 16384 + n * 2048);
    }
    SB0();
    __builtin_amdgcn_s_barrier();
}

__global__ __launch_bounds__(512, 2) void gemm_bf16_8phase(
    const __hip_bfloat16* __restrict__ A, const __hip_bfloat16* __restrict__ B,
    const float* __restrict__ bias, float* __restrict__ C)
{
    extern __shared__ char lds[];  // 131072 B

    const int tid = threadIdx.x;
    const int lane = tid & 63;
    const int wid = tid >> 6;       // 0..7
    const int wr = wid >> 2;        // 0..1 (M split)
    const int wc = wid & 3;         // 0..3 (N split)
    const int l15 = lane & 15;
    const int kgrp = lane >> 4;

    // XCD stripe (bijective) + 2D brick order (round-9): per-XCD 8x4 bricks.
    const int wg = blockIdx.x;
    const int s = (wg & 7) * (NWG / 8) + (wg >> 3);
    int bm, bn;
    if (s < 1280) {                 // 10 groups of width 4 (8x4 bricks)
        const int g = s >> 7;
        const int j = s & 127;
        bm = j >> 2;
        bn = g * 4 + (j & 3);
    } else {                        // last group: width 3
        const int j = s - 1280;     // 0..95
        bm = j / 3;
        bn = 40 + j % 3;
    }
    const int m0 = bm * BM;
    const int n0 = bn * BN;

    // ---- Precomputed stage-source element offsets (per lane, once) ----
    int sA_lo[2], sA_hi[2], sB_lo[2], sB_hi[2];
#pragma unroll
    for (int c = 0; c < 2; ++c) {
        const int idx = c * 512 + tid;          // 0..1023 chunk id (linear LDS)
        const int row = idx >> 3;               // 0..127
        const int scol = (idx & 7) ^ (row & 7); // pre-swizzled source chunk
        sA_lo[c] = (m0 + row) * K_DIM + scol * 8;
        sA_hi[c] = sA_lo[c] + 128 * K_DIM;
        sB_lo[c] = (n0 + row) * K_DIM + scol * 8;
        sB_hi[c] = sB_lo[c] + 128 * K_DIM;
    }
    const int dst0 = wid * 1024;          // (c*512 + wid*64)*16, c=0
    const int dst1 = 8192 + wid * 1024;   // c=1

    // ---- Precomputed fragment-read base pointers (buf0; buf1 = +65536) ----
    const int xlo = l15 & 7;
    const char* pA0 = lds + (wr * 64 + l15) * 128 + ((kgrp) ^ xlo) * 16;
    const char* pA1 = lds + (wr * 64 + l15) * 128 + ((4 + kgrp) ^ xlo) * 16;
    const char* pB0 = lds + 32768 + (wc * 32 + l15) * 128 + ((kgrp) ^ xlo) * 16;
    const char* pB1 = lds + 32768 + (wc * 32 + l15) * 128 + ((4 + kgrp) ^ xlo) * 16;

    // acc quadrants: 0=(0,0) 1=(0,1) 2=(1,1) 3=(1,0)  (mq,nq)
    f32x4 acc[4][4][2];
#pragma unroll
    for (int q = 0; q < 4; ++q)
#pragma unroll
        for (int m = 0; m < 4; ++m)
#pragma unroll
            for (int n = 0; n < 2; ++n)
                acc[q][m][n] = (f32x4){0.f, 0.f, 0.f, 0.f};

    // Fragment registers (live across windows)
    bf16x8 avLo[4][2], avHi[4][2], bvLo[2][2], bvHi[2][2];

    // Prologue pair-stream (FIFO matches steady state):
    //  {Alo(0),Blo(0)} ; {Ahi(0),Bhi(0)} ; {Alo(1),Blo(1)}
    STAGE(A, sA_lo[0], dst0);                 STAGE(A, sA_lo[1], dst1);
    STAGE(B, sB_lo[0], 32768 + dst0);         STAGE(B, sB_lo[1], 32768 + dst1);
    STAGE(A, sA_hi[0], 16384 + dst0);         STAGE(A, sA_hi[1], 16384 + dst1);
    STAGE(B, sB_hi[0], 49152 + dst0);         STAGE(B, sB_hi[1], 49152 + dst1);
    STAGE(A, sA_lo[0] + 64, 65536 + dst0);    STAGE(A, sA_lo[1] + 64, 65536 + dst1);
    STAGE(B, sB_lo[0] + 64, 98304 + dst0);    STAGE(B, sB_lo[1] + 64, 98304 + dst1);
    SB0();
    asm volatile("s_waitcnt vmcnt(4)");  // confirms {Alo,Blo}(0)+{Ahi,Bhi}(0)
    SB0();
    __builtin_amdgcn_s_barrier();
    SB0();
    // Prologue reads (the W1(-1) trail slot): avLo,bvLo,bvHi(0) <- buf0
#pragma unroll
    for (int m = 0; m < 4; ++m) {
        if (m < 2) bvLo[m][0] = *(const bf16x8*)(pB0 + m * 2048);
        avLo[m][0] = *(const bf16x8*)(pA0 + m * 2048);
    }
#pragma unroll
    for (int m = 0; m < 4; ++m) {
        if (m < 2) bvLo[m][1] = *(const bf16x8*)(pB1 + m * 2048);
        avLo[m][1] = *(const bf16x8*)(pA1 + m * 2048);
    }
#pragma unroll
    for (int n = 0; n < 2; ++n) {
        bvHi[n][0] = *(const bf16x8*)(pB0 + 16384 + n * 2048);
        bvHi[n][1] = *(const bf16x8*)(pB1 + 16384 + n * 2048);
    }
    SB0();
    __builtin_amdgcn_s_barrier();

    for (int t = 0; t < NT; t += 2) {
        tile_body<0>(t,     acc, A, B, lds, sA_lo, sA_hi, sB_lo, sB_hi,
                     dst0, dst1, pA0, pA1, pB0, pB1, avLo, avHi, bvLo, bvHi);
        tile_body<1>(t + 1, acc, A, B, lds, sA_lo, sA_hi, sB_lo, sB_hi,
                     dst0, dst1, pA0, pA1, pB0, pB1, avLo, avHi, bvLo, bvHi);
    }

    // Epilogue (C/D layout: col = lane&15, row = (lane>>4)*4 + reg).
    // Nontemporal: C written once, never re-read -> don't churn L3.
#pragma unroll
    for (int q = 0; q < 4; ++q) {
        const int mqe = q >> 1;
        const int nqe = (q == 1 || q == 2) ? 1 : 0;
#pragma unroll
        for (int n = 0; n < 2; ++n) {
            const int col = n0 + nqe * 128 + wc * 32 + n * 16 + l15;
            const float bval = bias[col];
#pragma unroll
            for (int m = 0; m < 4; ++m) {
                const int row = m0 + mqe * 128 + wr * 64 + m * 16 + kgrp * 4;
#pragma unroll
                for (int r = 0; r < 4; ++r)
                    __builtin_nontemporal_store(acc[q][m][n][r] + bval,
                        &C[(size_t)(row + r) * N_DIM + col]);
            }
        }
    }
}

// ---------------------------------------------------------------------------
extern "C" void kernel_launch(void* const* d_in, const int* in_sizes, int n_in,
                              void* d_out, int out_size, void* d_ws, size_t ws_size,
                              hipStream_t stream)
{
    const float* x      = (const float*)d_in[0];  // [4,2048,4096] f32
    const int*   codes  = (const int*)d_in[1];    // [704512,64] i32
    const float* absmax = (const float*)d_in[2];  // [704512] f32
    const float* bias   = (const float*)d_in[3];  // [11008] f32
    float* out = (float*)d_out;                   // [4,2048,11008] f32

    const size_t w_bytes = (size_t)N_DIM * K_DIM * sizeof(__hip_bfloat16);
    const size_t x_bytes = (size_t)M_DIM * K_DIM * sizeof(__hip_bfloat16);
    if (ws_size < w_bytes + x_bytes) {
        fprintf(stderr, "kernel_launch: ws_size=%zu < needed %zu\n",
                ws_size, w_bytes + x_bytes);
        return;
    }
    __hip_bfloat16* wbf = (__hip_bfloat16*)d_ws;
    __hip_bfloat16* xbf = (__hip_bfloat16*)((char*)d_ws + w_bytes);

    // Allow 128 KiB dynamic LDS (idempotent host-side call; capture-safe).
    hipFuncSetAttribute((const void*)gemm_bf16_8phase,
                        hipFuncAttributeMaxDynamicSharedMemorySize, 131072);

    prep_kernel<<<dim3(DEQ_BLOCKS + CVT_BLOCKS), dim3(256), 0, stream>>>(
        codes, absmax, x, wbf, xbf);
    gemm_bf16_8phase<<<dim3(NWG), dim3(512), 131072, stream>>>(xbf, wbf, bias, out);
}